// Round 1
// baseline (447.750 us; speedup 1.0000x reference)
//
#include <hip/hip_runtime.h>
#include <stdint.h>

#define M_TOT 8192
#define N_TOT 4096
#define K_TOT 4096

typedef short  s16x8 __attribute__((ext_vector_type(8)));
typedef unsigned short u16x8 __attribute__((ext_vector_type(8)));
typedef float  f32x4 __attribute__((ext_vector_type(4)));

__device__ __forceinline__ unsigned short f32_to_bf16(float f) {
  union { float f; unsigned u; } v; v.f = f;
  unsigned r = v.u + 0x7FFFu + ((v.u >> 16) & 1u);   // RNE
  return (unsigned short)(r >> 16);
}

__device__ __forceinline__ void gload_lds16(void* lds, const void* g) {
  __builtin_amdgcn_global_load_lds(
      (const __attribute__((address_space(1))) unsigned int*)g,
      (__attribute__((address_space(3))) unsigned int*)lds,
      16, 0, 0);
}

// ---- Prep 1: partial column sums of squares of (weight + tiled mora) ----
// grid (16, 32): 256 columns per block-x, 128 rows per block-y
__global__ void colnorm_partial_k(const float* __restrict__ weight,
                                  const float* __restrict__ mora,
                                  float* __restrict__ partials) {
  int d = blockIdx.x * 256 + threadIdx.x;
  int o0 = blockIdx.y * 128;
  float s = 0.f;
  #pragma unroll 4
  for (int o = o0; o < o0 + 128; ++o) {
    float w = weight[(size_t)o * K_TOT + d] + mora[(size_t)(o >> 1) * 2048 + (d >> 1)];
    s = fmaf(w, w, s);
  }
  partials[blockIdx.y * K_TOT + d] = s;
}

// ---- Prep 2: scale[d] = dora_mag[d] / sqrt(sum) ----
__global__ void scale_k(const float* __restrict__ partials,
                        const float* __restrict__ dora_mag,
                        float* __restrict__ scale) {
  int d = blockIdx.x * 256 + threadIdx.x;
  float s = 0.f;
  #pragma unroll
  for (int c = 0; c < 32; ++c) s += partials[c * K_TOT + d];
  scale[d] = dora_mag[d] / sqrtf(s);
}

// ---- Prep 3: w_bf16[o][d] = bf16((weight + mora_tiled) * scale[d]) ----
__global__ void pack_w_k(const float* __restrict__ weight,
                         const float* __restrict__ mora,
                         const float* __restrict__ scale,
                         unsigned short* __restrict__ wb) {
  size_t idx = ((size_t)blockIdx.x * 256 + threadIdx.x) * 8;
  int o = (int)(idx >> 12);
  int d = (int)(idx & (K_TOT - 1));
  float4 w0 = *(const float4*)(weight + idx);
  float4 w1 = *(const float4*)(weight + idx + 4);
  float4 mv = *(const float4*)(mora + (size_t)(o >> 1) * 2048 + (d >> 1));
  float4 s0 = *(const float4*)(scale + d);
  float4 s1 = *(const float4*)(scale + d + 4);
  u16x8 r;
  r[0] = f32_to_bf16((w0.x + mv.x) * s0.x);
  r[1] = f32_to_bf16((w0.y + mv.x) * s0.y);
  r[2] = f32_to_bf16((w0.z + mv.y) * s0.z);
  r[3] = f32_to_bf16((w0.w + mv.y) * s0.w);
  r[4] = f32_to_bf16((w1.x + mv.z) * s1.x);
  r[5] = f32_to_bf16((w1.y + mv.z) * s1.y);
  r[6] = f32_to_bf16((w1.z + mv.w) * s1.z);
  r[7] = f32_to_bf16((w1.w + mv.w) * s1.w);
  *(u16x8*)(wb + idx) = r;
}

// ---- Prep 4: x -> bf16 ----
__global__ void pack_x_k(const float* __restrict__ x, unsigned short* __restrict__ xb) {
  size_t idx = ((size_t)blockIdx.x * 256 + threadIdx.x) * 8;
  float4 v0 = *(const float4*)(x + idx);
  float4 v1 = *(const float4*)(x + idx + 4);
  u16x8 r;
  r[0] = f32_to_bf16(v0.x); r[1] = f32_to_bf16(v0.y);
  r[2] = f32_to_bf16(v0.z); r[3] = f32_to_bf16(v0.w);
  r[4] = f32_to_bf16(v1.x); r[5] = f32_to_bf16(v1.y);
  r[6] = f32_to_bf16(v1.z); r[7] = f32_to_bf16(v1.w);
  *(u16x8*)(xb + idx) = r;
}

// ---- Main GEMM: out[m][o] = sum_d xb[m][d] * wb[o][d]  (both row-major [*, K]) ----
// m97 structure: 128x128 tile, BK=64, 4 waves (2x2 of 64x64), 16x16x32 bf16 MFMA,
// global_load_lds width 16, single-buffered LDS, 2 barriers per K-step.
__global__ void __launch_bounds__(256) gemm_bf16_k(
    const unsigned short* __restrict__ xb,   // [8192][4096]
    const unsigned short* __restrict__ wb,   // [4096][4096]
    float* __restrict__ out) {               // [8192][4096]
  __shared__ short As[128 * 64];             // [m][k]
  __shared__ short Bs[128 * 64];             // [n][k]
  const int t = threadIdx.x;
  const int l = t & 63;
  const int w = t >> 6;
  const int wr = w >> 1, wc = w & 1;         // 2x2 wave grid, 64x64 each
  const int bx = blockIdx.x;                 // N tile (32)
  const int by = blockIdx.y;                 // M tile (64)

  const int lrow = l & 15;
  const int lko  = (l >> 4) * 8;

  f32x4 acc[4][4] = {};

  const unsigned short* ag = xb + (size_t)(by * 128) * K_TOT;
  const unsigned short* bg = wb + (size_t)(bx * 128) * K_TOT;

  for (int kt = 0; kt < K_TOT; kt += 64) {
    // stage A and B tiles: 1024 chunks of 16B each per tile, 4 rounds x 256 thr
    #pragma unroll
    for (int r = 0; r < 4; ++r) {
      int c = r * 256 + t;
      int row = c >> 3;                      // 8 chunks per 64-col row
      int col = (c & 7) * 8;
      int ldsbase = (r * 256 + (t & ~63)) * 8;   // wave-uniform; HW adds lane*16B
      gload_lds16(&As[ldsbase], ag + (size_t)row * K_TOT + kt + col);
      gload_lds16(&Bs[ldsbase], bg + (size_t)row * K_TOT + kt + col);
    }
    __syncthreads();   // drains vmcnt(0) -> LDS tiles complete
    #pragma unroll
    for (int kk = 0; kk < 2; ++kk) {
      s16x8 a[4], b[4];
      const int ko = kk * 32 + lko;
      #pragma unroll
      for (int m = 0; m < 4; ++m)
        a[m] = *(const s16x8*)&As[(wr * 64 + m * 16 + lrow) * 64 + ko];
      #pragma unroll
      for (int n = 0; n < 4; ++n)
        b[n] = *(const s16x8*)&Bs[(wc * 64 + n * 16 + lrow) * 64 + ko];
      #pragma unroll
      for (int m = 0; m < 4; ++m)
        #pragma unroll
        for (int n = 0; n < 4; ++n)
          acc[m][n] = __builtin_amdgcn_mfma_f32_16x16x32_bf16(a[m], b[n], acc[m][n], 0, 0, 0);
    }
    __syncthreads();
  }

  // C/D layout (verified m89/m91): col = lane&15, row = (lane>>4)*4 + reg
  const int row0 = by * 128 + wr * 64 + (l >> 4) * 4;
  const int col0 = bx * 128 + wc * 64 + (l & 15);
  #pragma unroll
  for (int m = 0; m < 4; ++m)
    #pragma unroll
    for (int n = 0; n < 4; ++n) {
      const int rr = row0 + m * 16;
      const int cc = col0 + n * 16;
      #pragma unroll
      for (int j = 0; j < 4; ++j)
        out[(size_t)(rr + j) * N_TOT + cc] = acc[m][n][j];
    }
}

// ---- Fallback fp32 GEMM (only if ws too small for bf16 copies) ----
__global__ void gemm_fb_k(const float* __restrict__ x, const float* __restrict__ weight,
                          const float* __restrict__ mora, const float* __restrict__ scale,
                          float* __restrict__ out) {
  __shared__ float As[64][17];
  __shared__ float Bs[64][17];
  int t = threadIdx.x;
  int bx = blockIdx.x, by = blockIdx.y;
  int tr = t >> 4, tc = t & 15;
  float c[4][4] = {};
  for (int kt = 0; kt < K_TOT; kt += 16) {
    #pragma unroll
    for (int r = 0; r < 4; ++r) {
      int idx = r * 256 + t;
      int row = idx >> 4, col = idx & 15;
      As[row][col] = x[(size_t)(by * 64 + row) * K_TOT + kt + col];
      int o = bx * 64 + row, d = kt + col;
      Bs[row][col] = (weight[(size_t)o * K_TOT + d] + mora[(size_t)(o >> 1) * 2048 + (d >> 1)]) * scale[d];
    }
    __syncthreads();
    #pragma unroll
    for (int k = 0; k < 16; ++k) {
      float av[4], bv[4];
      #pragma unroll
      for (int i = 0; i < 4; ++i) av[i] = As[tr * 4 + i][k];
      #pragma unroll
      for (int j = 0; j < 4; ++j) bv[j] = Bs[tc * 4 + j][k];
      #pragma unroll
      for (int i = 0; i < 4; ++i)
        #pragma unroll
        for (int j = 0; j < 4; ++j)
          c[i][j] = fmaf(av[i], bv[j], c[i][j]);
    }
    __syncthreads();
  }
  #pragma unroll
  for (int i = 0; i < 4; ++i)
    #pragma unroll
    for (int j = 0; j < 4; ++j)
      out[(size_t)(by * 64 + tr * 4 + i) * N_TOT + bx * 64 + tc * 4 + j] = c[i][j];
}

extern "C" void kernel_launch(void* const* d_in, const int* in_sizes, int n_in,
                              void* d_out, int out_size, void* d_ws, size_t ws_size,
                              hipStream_t stream) {
  const float* x      = (const float*)d_in[0];   // (4,2048,4096) f32
  const float* weight = (const float*)d_in[1];   // (4096,4096)   f32
  const float* mora   = (const float*)d_in[2];   // (2048,2048)   f32
  const float* dora   = (const float*)d_in[3];   // (1,4096)      f32
  float* out = (float*)d_out;                    // (4,2048,4096) f32

  char* ws = (char*)d_ws;
  float* partials = (float*)ws;                         // 32*4096*4 = 512 KB
  float* scale    = (float*)(ws + (512 << 10));         // 16 KB
  const size_t OFF_W = (size_t)1 << 20;
  unsigned short* wb = (unsigned short*)(ws + OFF_W);                              // 32 MB
  unsigned short* xb = (unsigned short*)(ws + OFF_W + (size_t)N_TOT * K_TOT * 2);  // 64 MB
  const size_t NEED = OFF_W + (size_t)N_TOT * K_TOT * 2 + (size_t)M_TOT * K_TOT * 2;

  dim3 b256(256);
  colnorm_partial_k<<<dim3(16, 32), b256, 0, stream>>>(weight, mora, partials);
  scale_k<<<16, b256, 0, stream>>>(partials, dora, scale);

  if (ws_size >= NEED) {
    pack_w_k<<<(N_TOT * K_TOT) / (256 * 8), b256, 0, stream>>>(weight, mora, scale, wb);
    pack_x_k<<<(M_TOT * K_TOT) / (256 * 8), b256, 0, stream>>>(x, xb);
    gemm_bf16_k<<<dim3(N_TOT / 128, M_TOT / 128), b256, 0, stream>>>(xb, wb, out);
  } else {
    gemm_fb_k<<<dim3(N_TOT / 64, M_TOT / 64), b256, 0, stream>>>(x, weight, mora, scale, out);
  }
}

// Round 2
// 338.468 us; speedup vs baseline: 1.3229x; 1.3229x over previous
//
#include <hip/hip_runtime.h>
#include <stdint.h>

#define M_TOT 8192
#define N_TOT 4096
#define K_TOT 4096
#define BM 256
#define BN 256
#define BK 32
#define NT (K_TOT / BK)   // 128 K-steps

typedef short  s16x8 __attribute__((ext_vector_type(8)));
typedef unsigned short u16x8 __attribute__((ext_vector_type(8)));
typedef float  f32x4 __attribute__((ext_vector_type(4)));

__device__ __forceinline__ unsigned short f32_to_bf16(float f) {
  union { float f; unsigned u; } v; v.f = f;
  unsigned r = v.u + 0x7FFFu + ((v.u >> 16) & 1u);   // RNE
  return (unsigned short)(r >> 16);
}

__device__ __forceinline__ void gload_lds16(void* lds, const void* g) {
  __builtin_amdgcn_global_load_lds(
      (const __attribute__((address_space(1))) unsigned int*)g,
      (__attribute__((address_space(3))) unsigned int*)lds,
      16, 0, 0);
}

// ---- Prep 1: partial column sums of squares of (weight + tiled mora) ----
__global__ void colnorm_partial_k(const float* __restrict__ weight,
                                  const float* __restrict__ mora,
                                  float* __restrict__ partials) {
  int d = blockIdx.x * 256 + threadIdx.x;
  int o0 = blockIdx.y * 128;
  float s = 0.f;
  #pragma unroll 4
  for (int o = o0; o < o0 + 128; ++o) {
    float w = weight[(size_t)o * K_TOT + d] + mora[(size_t)(o >> 1) * 2048 + (d >> 1)];
    s = fmaf(w, w, s);
  }
  partials[blockIdx.y * K_TOT + d] = s;
}

// ---- Prep 2: scale[d] = dora_mag[d] / sqrt(sum) ----
__global__ void scale_k(const float* __restrict__ partials,
                        const float* __restrict__ dora_mag,
                        float* __restrict__ scale) {
  int d = blockIdx.x * 256 + threadIdx.x;
  float s = 0.f;
  #pragma unroll
  for (int c = 0; c < 32; ++c) s += partials[c * K_TOT + d];
  scale[d] = dora_mag[d] / sqrtf(s);
}

// ---- Prep 3: w_bf16[o][d] = bf16((weight + mora_tiled) * scale[d]) ----
__global__ void pack_w_k(const float* __restrict__ weight,
                         const float* __restrict__ mora,
                         const float* __restrict__ scale,
                         unsigned short* __restrict__ wb) {
  size_t idx = ((size_t)blockIdx.x * 256 + threadIdx.x) * 8;
  int o = (int)(idx >> 12);
  int d = (int)(idx & (K_TOT - 1));
  float4 w0 = *(const float4*)(weight + idx);
  float4 w1 = *(const float4*)(weight + idx + 4);
  float4 mv = *(const float4*)(mora + (size_t)(o >> 1) * 2048 + (d >> 1));
  float4 s0 = *(const float4*)(scale + d);
  float4 s1 = *(const float4*)(scale + d + 4);
  u16x8 r;
  r[0] = f32_to_bf16((w0.x + mv.x) * s0.x);
  r[1] = f32_to_bf16((w0.y + mv.x) * s0.y);
  r[2] = f32_to_bf16((w0.z + mv.y) * s0.z);
  r[3] = f32_to_bf16((w0.w + mv.y) * s0.w);
  r[4] = f32_to_bf16((w1.x + mv.z) * s1.x);
  r[5] = f32_to_bf16((w1.y + mv.z) * s1.y);
  r[6] = f32_to_bf16((w1.z + mv.w) * s1.z);
  r[7] = f32_to_bf16((w1.w + mv.w) * s1.w);
  *(u16x8*)(wb + idx) = r;
}

// ---- Prep 4: x -> bf16 ----
__global__ void pack_x_k(const float* __restrict__ x, unsigned short* __restrict__ xb) {
  size_t idx = ((size_t)blockIdx.x * 256 + threadIdx.x) * 8;
  float4 v0 = *(const float4*)(x + idx);
  float4 v1 = *(const float4*)(x + idx + 4);
  u16x8 r;
  r[0] = f32_to_bf16(v0.x); r[1] = f32_to_bf16(v0.y);
  r[2] = f32_to_bf16(v0.z); r[3] = f32_to_bf16(v0.w);
  r[4] = f32_to_bf16(v1.x); r[5] = f32_to_bf16(v1.y);
  r[6] = f32_to_bf16(v1.z); r[7] = f32_to_bf16(v1.w);
  *(u16x8*)(xb + idx) = r;
}

// ---- Main GEMM: 256x256 tile, BK=32, 8 waves (2x4), 4-deep LDS ring,
// counted vmcnt pipeline (one barrier per K-step, loads span barriers). ----
__device__ __forceinline__ void stage_tile(
    const unsigned short* ga0, const unsigned short* ga1,
    const unsigned short* gb0, const unsigned short* gb1,
    short* la, short* lb, int lo0, int lo1, int kt) {
  gload_lds16(la + lo0, ga0 + kt);
  gload_lds16(lb + lo0, gb0 + kt);
  gload_lds16(la + lo1, ga1 + kt);
  gload_lds16(lb + lo1, gb1 + kt);
}

__device__ __forceinline__ void compute_tile(
    const short* la, const short* lb, int aoff, int boff, f32x4 (&acc)[8][4]) {
  s16x8 bfr[4], afr[8];
  #pragma unroll
  for (int n = 0; n < 4; ++n)
    bfr[n] = *(const s16x8*)(lb + boff + n * 16 * BK);
  #pragma unroll
  for (int m = 0; m < 8; ++m)
    afr[m] = *(const s16x8*)(la + aoff + m * 16 * BK);
  __builtin_amdgcn_s_setprio(1);
  #pragma unroll
  for (int m = 0; m < 8; ++m)
    #pragma unroll
    for (int n = 0; n < 4; ++n)
      acc[m][n] = __builtin_amdgcn_mfma_f32_16x16x32_bf16(afr[m], bfr[n], acc[m][n], 0, 0, 0);
  __builtin_amdgcn_s_setprio(0);
}

__global__ void __launch_bounds__(512, 2) gemm_bf16_k(
    const unsigned short* __restrict__ xb,   // [8192][4096]
    const unsigned short* __restrict__ wb,   // [4096][4096]
    float* __restrict__ out) {               // [8192][4096]
  __shared__ short lds[4][2][BM * BK];       // 4 ring buffers x (A,B) x 16KB = 128KB

  const int tid = threadIdx.x;
  const int l   = tid & 63;
  const int wid = tid >> 6;
  const int wm  = wid >> 2;                  // 0..1 -> M rows wm*128
  const int wn  = wid & 3;                   // 0..3 -> N cols wn*64

  // XCD-aware bijective swizzle (nwg=512, divisible by 8)
  const int orig = blockIdx.x;
  const int swz  = (orig & 7) * (512 >> 3) + (orig >> 3);
  const int by = swz >> 4;                   // 0..31
  const int bx = swz & 15;                   // 0..15

  const unsigned short* ag = xb + (size_t)(by * BM) * K_TOT;
  const unsigned short* bg = wb + (size_t)(bx * BN) * K_TOT;

  // staging: 1024 16B-chunks per operand tile; chunk c: row=c>>2, col=(c&3)*8
  const int c0 = tid, c1 = 512 + tid;
  const unsigned short* ga0 = ag + (size_t)(c0 >> 2) * K_TOT + (c0 & 3) * 8;
  const unsigned short* ga1 = ag + (size_t)(c1 >> 2) * K_TOT + (c1 & 3) * 8;
  const unsigned short* gb0 = bg + (size_t)(c0 >> 2) * K_TOT + (c0 & 3) * 8;
  const unsigned short* gb1 = bg + (size_t)(c1 >> 2) * K_TOT + (c1 & 3) * 8;
  const int lo0 = (tid & ~63) * 8;           // wave-uniform LDS base (shorts)
  const int lo1 = (512 + (tid & ~63)) * 8;

  const int lrow = l & 15;
  const int lko  = (l >> 4) * 8;
  const int aoff = (wm * 128 + lrow) * BK + lko;
  const int boff = (wn * 64  + lrow) * BK + lko;

  f32x4 acc[8][4] = {};

  #define STG(t) stage_tile(ga0, ga1, gb0, gb1, lds[(t) & 3][0], lds[(t) & 3][1], lo0, lo1, (t) * BK)
  #define CMP(t) compute_tile(lds[(t) & 3][0], lds[(t) & 3][1], aoff, boff, acc)

  STG(0); STG(1); STG(2);

  #pragma unroll 1
  for (int t = 0; t < NT - 3; ++t) {
    asm volatile("s_waitcnt vmcnt(8)" ::: "memory");  // oldest stage (tile t) complete
    __builtin_amdgcn_s_barrier();                     // all waves staged t; buf[(t+3)&3] free
    STG(t + 3);
    CMP(t);
  }
  asm volatile("s_waitcnt vmcnt(8)" ::: "memory");
  __builtin_amdgcn_s_barrier();
  CMP(NT - 3);
  asm volatile("s_waitcnt vmcnt(4)" ::: "memory");
  __builtin_amdgcn_s_barrier();
  CMP(NT - 2);
  asm volatile("s_waitcnt vmcnt(0)" ::: "memory");
  __builtin_amdgcn_s_barrier();
  CMP(NT - 1);

  #undef STG
  #undef CMP

  // C/D layout (verified R1): col = lane&15, row = (lane>>4)*4 + reg
  const int row0 = by * BM + wm * 128 + (l >> 4) * 4;
  const int col0 = bx * BN + wn * 64 + lrow;
  #pragma unroll
  for (int m = 0; m < 8; ++m)
    #pragma unroll
    for (int n = 0; n < 4; ++n) {
      #pragma unroll
      for (int j = 0; j < 4; ++j)
        out[(size_t)(row0 + m * 16 + j) * N_TOT + col0 + n * 16] = acc[m][n][j];
    }
}

// ---- Fallback fp32 GEMM (only if ws too small for bf16 copies) ----
__global__ void gemm_fb_k(const float* __restrict__ x, const float* __restrict__ weight,
                          const float* __restrict__ mora, const float* __restrict__ scale,
                          float* __restrict__ out) {
  __shared__ float As[64][17];
  __shared__ float Bs[64][17];
  int t = threadIdx.x;
  int bx = blockIdx.x, by = blockIdx.y;
  int tr = t >> 4, tc = t & 15;
  float c[4][4] = {};
  for (int kt = 0; kt < K_TOT; kt += 16) {
    #pragma unroll
    for (int r = 0; r < 4; ++r) {
      int idx = r * 256 + t;
      int row = idx >> 4, col = idx & 15;
      As[row][col] = x[(size_t)(by * 64 + row) * K_TOT + kt + col];
      int o = bx * 64 + row, d = kt + col;
      Bs[row][col] = (weight[(size_t)o * K_TOT + d] + mora[(size_t)(o >> 1) * 2048 + (d >> 1)]) * scale[d];
    }
    __syncthreads();
    #pragma unroll
    for (int k = 0; k < 16; ++k) {
      float av[4], bv[4];
      #pragma unroll
      for (int i = 0; i < 4; ++i) av[i] = As[tr * 4 + i][k];
      #pragma unroll
      for (int j = 0; j < 4; ++j) bv[j] = Bs[tc * 4 + j][k];
      #pragma unroll
      for (int i = 0; i < 4; ++i)
        #pragma unroll
        for (int j = 0; j < 4; ++j)
          c[i][j] = fmaf(av[i], bv[j], c[i][j]);
    }
    __syncthreads();
  }
  #pragma unroll
  for (int i = 0; i < 4; ++i)
    #pragma unroll
    for (int j = 0; j < 4; ++j)
      out[(size_t)(by * 64 + tr * 4 + i) * N_TOT + bx * 64 + tc * 4 + j] = c[i][j];
}

extern "C" void kernel_launch(void* const* d_in, const int* in_sizes, int n_in,
                              void* d_out, int out_size, void* d_ws, size_t ws_size,
                              hipStream_t stream) {
  const float* x      = (const float*)d_in[0];   // (4,2048,4096) f32
  const float* weight = (const float*)d_in[1];   // (4096,4096)   f32
  const float* mora   = (const float*)d_in[2];   // (2048,2048)   f32
  const float* dora   = (const float*)d_in[3];   // (1,4096)      f32
  float* out = (float*)d_out;                    // (4,2048,4096) f32

  char* ws = (char*)d_ws;
  float* partials = (float*)ws;                         // 512 KB
  float* scale    = (float*)(ws + (512 << 10));         // 16 KB
  const size_t OFF_W = (size_t)1 << 20;
  unsigned short* wbuf = (unsigned short*)(ws + OFF_W);                              // 32 MB
  unsigned short* xbuf = (unsigned short*)(ws + OFF_W + (size_t)N_TOT * K_TOT * 2);  // 64 MB
  const size_t NEED = OFF_W + (size_t)N_TOT * K_TOT * 2 + (size_t)M_TOT * K_TOT * 2;

  dim3 b256(256);
  colnorm_partial_k<<<dim3(16, 32), b256, 0, stream>>>(weight, mora, partials);
  scale_k<<<16, b256, 0, stream>>>(partials, dora, scale);

  if (ws_size >= NEED) {
    pack_w_k<<<(N_TOT * K_TOT) / (256 * 8), b256, 0, stream>>>(weight, mora, scale, wbuf);
    pack_x_k<<<(M_TOT * K_TOT) / (256 * 8), b256, 0, stream>>>(x, xbuf);
    gemm_bf16_k<<<(M_TOT / BM) * (N_TOT / BN), 512, 0, stream>>>(xbuf, wbuf, out);
  } else {
    gemm_fb_k<<<dim3(N_TOT / 64, M_TOT / 64), b256, 0, stream>>>(x, weight, mora, scale, out);
  }
}

// Round 3
// 336.341 us; speedup vs baseline: 1.3312x; 1.0063x over previous
//
#include <hip/hip_runtime.h>
#include <stdint.h>

#define M_TOT 8192
#define N_TOT 4096
#define K_TOT 4096
#define BM 256
#define BN 256
#define BK 32
#define NT (K_TOT / BK)   // 128 K-tiles

typedef short  s16x8 __attribute__((ext_vector_type(8)));
typedef unsigned short u16x8 __attribute__((ext_vector_type(8)));
typedef float  f32x4 __attribute__((ext_vector_type(4)));

__device__ __forceinline__ unsigned short f32_to_bf16(float f) {
  union { float f; unsigned u; } v; v.f = f;
  unsigned r = v.u + 0x7FFFu + ((v.u >> 16) & 1u);   // RNE
  return (unsigned short)(r >> 16);
}

__device__ __forceinline__ void gload_lds16(void* lds, const void* g) {
  __builtin_amdgcn_global_load_lds(
      (const __attribute__((address_space(1))) unsigned int*)g,
      (__attribute__((address_space(3))) unsigned int*)lds,
      16, 0, 0);
}

// ---- Prep 1: partial column sums of squares of (weight + tiled mora) ----
__global__ void colnorm_partial_k(const float* __restrict__ weight,
                                  const float* __restrict__ mora,
                                  float* __restrict__ partials) {
  int d = blockIdx.x * 256 + threadIdx.x;
  int o0 = blockIdx.y * 128;
  float s = 0.f;
  #pragma unroll 4
  for (int o = o0; o < o0 + 128; ++o) {
    float w = weight[(size_t)o * K_TOT + d] + mora[(size_t)(o >> 1) * 2048 + (d >> 1)];
    s = fmaf(w, w, s);
  }
  partials[blockIdx.y * K_TOT + d] = s;
}

// ---- Prep 2: scale[d] = dora_mag[d] / sqrt(sum) ----
__global__ void scale_k(const float* __restrict__ partials,
                        const float* __restrict__ dora_mag,
                        float* __restrict__ scale) {
  int d = blockIdx.x * 256 + threadIdx.x;
  float s = 0.f;
  #pragma unroll
  for (int c = 0; c < 32; ++c) s += partials[c * K_TOT + d];
  scale[d] = dora_mag[d] / sqrtf(s);
}

// ---- Prep 3: w_bf16[o][d] = bf16((weight + mora_tiled) * scale[d]) ----
__global__ void pack_w_k(const float* __restrict__ weight,
                         const float* __restrict__ mora,
                         const float* __restrict__ scale,
                         unsigned short* __restrict__ wb) {
  size_t idx = ((size_t)blockIdx.x * 256 + threadIdx.x) * 8;
  int o = (int)(idx >> 12);
  int d = (int)(idx & (K_TOT - 1));
  float4 w0 = *(const float4*)(weight + idx);
  float4 w1 = *(const float4*)(weight + idx + 4);
  float4 mv = *(const float4*)(mora + (size_t)(o >> 1) * 2048 + (d >> 1));
  float4 s0 = *(const float4*)(scale + d);
  float4 s1 = *(const float4*)(scale + d + 4);
  u16x8 r;
  r[0] = f32_to_bf16((w0.x + mv.x) * s0.x);
  r[1] = f32_to_bf16((w0.y + mv.x) * s0.y);
  r[2] = f32_to_bf16((w0.z + mv.y) * s0.z);
  r[3] = f32_to_bf16((w0.w + mv.y) * s0.w);
  r[4] = f32_to_bf16((w1.x + mv.z) * s1.x);
  r[5] = f32_to_bf16((w1.y + mv.z) * s1.y);
  r[6] = f32_to_bf16((w1.z + mv.w) * s1.z);
  r[7] = f32_to_bf16((w1.w + mv.w) * s1.w);
  *(u16x8*)(wb + idx) = r;
}

// ---- Prep 4: x -> bf16 ----
__global__ void pack_x_k(const float* __restrict__ x, unsigned short* __restrict__ xb) {
  size_t idx = ((size_t)blockIdx.x * 256 + threadIdx.x) * 8;
  float4 v0 = *(const float4*)(x + idx);
  float4 v1 = *(const float4*)(x + idx + 4);
  u16x8 r;
  r[0] = f32_to_bf16(v0.x); r[1] = f32_to_bf16(v0.y);
  r[2] = f32_to_bf16(v0.z); r[3] = f32_to_bf16(v0.w);
  r[4] = f32_to_bf16(v1.x); r[5] = f32_to_bf16(v1.y);
  r[6] = f32_to_bf16(v1.z); r[7] = f32_to_bf16(v1.w);
  *(u16x8*)(xb + idx) = r;
}

// ---- Main GEMM: 256x256 tile, BK=32, 8 waves (2x4), ring-4 LDS,
// 4 fine phases per 2 K-tiles, counted vmcnt (never 0 in main loop),
// setprio around MFMA clusters (T3+T4+T5). ----
__global__ void __launch_bounds__(512, 2) gemm_bf16_k(
    const unsigned short* __restrict__ xb,   // [8192][4096]
    const unsigned short* __restrict__ wb,   // [4096][4096]
    float* __restrict__ out) {               // [8192][4096]
  __shared__ short lds[4][2][BM * BK];       // 4 ring x (A,B) x 16KB = 128KB

  const int tid = threadIdx.x;
  const int l   = tid & 63;
  const int wid = tid >> 6;
  const int wm  = wid >> 2;                  // 0..1 -> M rows wm*128
  const int wn  = wid & 3;                   // 0..3 -> N cols wn*64

  // XCD-aware bijective swizzle (nwg=512, divisible by 8)
  const int orig = blockIdx.x;
  const int swz  = (orig & 7) * (512 >> 3) + (orig >> 3);
  const int by = swz >> 4;                   // 0..31
  const int bx = swz & 15;                   // 0..15

  const unsigned short* ag = xb + (size_t)(by * BM) * K_TOT;
  const unsigned short* bg = wb + (size_t)(bx * BN) * K_TOT;

  // staging: 1024 16B-chunks per operand K-tile; chunk c: row=c>>2, col=(c&3)*8
  const int c0 = tid, c1 = 512 + tid;
  const unsigned short* gA0 = ag + (size_t)(c0 >> 2) * K_TOT + (c0 & 3) * 8;
  const unsigned short* gA1 = ag + (size_t)(c1 >> 2) * K_TOT + (c1 & 3) * 8;
  const unsigned short* gB0 = bg + (size_t)(c0 >> 2) * K_TOT + (c0 & 3) * 8;
  const unsigned short* gB1 = bg + (size_t)(c1 >> 2) * K_TOT + (c1 & 3) * 8;
  const int lo0 = (tid & ~63) * 8;           // wave-uniform LDS base (shorts)
  const int lo1 = lo0 + 512 * 8;

  const int lrow = l & 15;
  const int lko  = (l >> 4) * 8;
  const int aoffb = (wm * 128 + lrow) * BK + lko;
  const int boffb = (wn * 64  + lrow) * BK + lko;

  s16x8 afr[4], bfr[4];
  f32x4 acc[8][4] = {};

#define STG_A(t) { short* p = &lds[(t) & 3][0][0]; \
    gload_lds16(p + lo0, gA0 + (size_t)(t) * BK); \
    gload_lds16(p + lo1, gA1 + (size_t)(t) * BK); }
#define STG_B(t) { short* p = &lds[(t) & 3][1][0]; \
    gload_lds16(p + lo0, gB0 + (size_t)(t) * BK); \
    gload_lds16(p + lo1, gB1 + (size_t)(t) * BK); }
#define DS_A(t, mb) { const short* p = &lds[(t) & 3][0][aoffb + (mb) * 16 * BK]; \
    afr[0] = *(const s16x8*)(p);               afr[1] = *(const s16x8*)(p + 16 * BK); \
    afr[2] = *(const s16x8*)(p + 32 * BK);     afr[3] = *(const s16x8*)(p + 48 * BK); }
#define DS_B(t) { const short* p = &lds[(t) & 3][1][boffb]; \
    bfr[0] = *(const s16x8*)(p);               bfr[1] = *(const s16x8*)(p + 16 * BK); \
    bfr[2] = *(const s16x8*)(p + 32 * BK);     bfr[3] = *(const s16x8*)(p + 48 * BK); }
#define BAR() __builtin_amdgcn_s_barrier()
#define LGKM0() asm volatile("s_waitcnt lgkmcnt(0)" ::: "memory")
#define VM8() asm volatile("s_waitcnt vmcnt(8)" ::: "memory")
#define VM4() asm volatile("s_waitcnt vmcnt(4)" ::: "memory")
#define VM0() asm volatile("s_waitcnt vmcnt(0)" ::: "memory")
#define MM(mb) { __builtin_amdgcn_s_setprio(1); \
    _Pragma("unroll") for (int mm = 0; mm < 4; ++mm) { \
      _Pragma("unroll") for (int nn = 0; nn < 4; ++nn) \
        acc[(mb) + mm][nn] = __builtin_amdgcn_mfma_f32_16x16x32_bf16(afr[mm], bfr[nn], acc[(mb) + mm][nn], 0, 0, 0); } \
    __builtin_amdgcn_s_setprio(0); }

  // prologue: 3 K-tiles staged (12 loads/thread in flight)
  STG_A(0); STG_B(0); STG_A(1); STG_B(1); STG_A(2); STG_B(2);
  VM8(); BAR();                               // tile 0 complete

  #pragma unroll 1
  for (int t = 0; t < NT - 4; t += 2) {
    // phase 1: tile t, quadrant m0-3
    DS_A(t, 0); DS_B(t);
    STG_A(t + 3);
    BAR(); LGKM0(); MM(0); BAR();
    // phase 2: tile t, quadrant m4-7 (bfr reused)
    DS_A(t, 4);
    STG_B(t + 3);
    BAR(); LGKM0(); MM(4);
    VM8(); BAR();                             // tile t+1 complete
    // phase 3: tile t+1, quadrant m0-3
    DS_A(t + 1, 0); DS_B(t + 1);
    STG_A(t + 4);
    BAR(); LGKM0(); MM(0); BAR();
    // phase 4: tile t+1, quadrant m4-7
    DS_A(t + 1, 4);
    STG_B(t + 4);
    BAR(); LGKM0(); MM(4);
    VM8(); BAR();                             // tile t+2 complete
  }

  // peel tiles 124,125 (stage only tile 127)
  DS_A(124, 0); DS_B(124);
  STG_A(127);
  BAR(); LGKM0(); MM(0); BAR();
  DS_A(124, 4);
  STG_B(127);
  BAR(); LGKM0(); MM(4);
  VM8(); BAR();                               // tile 125 complete
  DS_A(125, 0); DS_B(125);
  BAR(); LGKM0(); MM(0); BAR();
  DS_A(125, 4);
  BAR(); LGKM0(); MM(4);
  VM4(); BAR();                               // tile 126 complete
  // peel tiles 126,127 (no staging)
  DS_A(126, 0); DS_B(126);
  BAR(); LGKM0(); MM(0); BAR();
  DS_A(126, 4);
  BAR(); LGKM0(); MM(4);
  VM0(); BAR();                               // tile 127 complete
  DS_A(127, 0); DS_B(127);
  BAR(); LGKM0(); MM(0); BAR();
  DS_A(127, 4);
  LGKM0(); MM(4);

#undef STG_A
#undef STG_B
#undef DS_A
#undef DS_B
#undef MM

  // C/D layout (verified R1/R2): col = lane&15, row = (lane>>4)*4 + reg
  const int row0 = by * BM + wm * 128 + (l >> 4) * 4;
  const int col0 = bx * BN + wn * 64 + lrow;
  #pragma unroll
  for (int m = 0; m < 8; ++m)
    #pragma unroll
    for (int n = 0; n < 4; ++n) {
      #pragma unroll
      for (int j = 0; j < 4; ++j)
        out[(size_t)(row0 + m * 16 + j) * N_TOT + col0 + n * 16] = acc[m][n][j];
    }
}

// ---- Fallback fp32 GEMM (only if ws too small for bf16 copies) ----
__global__ void gemm_fb_k(const float* __restrict__ x, const float* __restrict__ weight,
                          const float* __restrict__ mora, const float* __restrict__ scale,
                          float* __restrict__ out) {
  __shared__ float As[64][17];
  __shared__ float Bs[64][17];
  int t = threadIdx.x;
  int bx = blockIdx.x, by = blockIdx.y;
  int tr = t >> 4, tc = t & 15;
  float c[4][4] = {};
  for (int kt = 0; kt < K_TOT; kt += 16) {
    #pragma unroll
    for (int r = 0; r < 4; ++r) {
      int idx = r * 256 + t;
      int row = idx >> 4, col = idx & 15;
      As[row][col] = x[(size_t)(by * 64 + row) * K_TOT + kt + col];
      int o = bx * 64 + row, d = kt + col;
      Bs[row][col] = (weight[(size_t)o * K_TOT + d] + mora[(size_t)(o >> 1) * 2048 + (d >> 1)]) * scale[d];
    }
    __syncthreads();
    #pragma unroll
    for (int k = 0; k < 16; ++k) {
      float av[4], bv[4];
      #pragma unroll
      for (int i = 0; i < 4; ++i) av[i] = As[tr * 4 + i][k];
      #pragma unroll
      for (int j = 0; j < 4; ++j) bv[j] = Bs[tc * 4 + j][k];
      #pragma unroll
      for (int i = 0; i < 4; ++i)
        #pragma unroll
        for (int j = 0; j < 4; ++j)
          c[i][j] = fmaf(av[i], bv[j], c[i][j]);
    }
    __syncthreads();
  }
  #pragma unroll
  for (int i = 0; i < 4; ++i)
    #pragma unroll
    for (int j = 0; j < 4; ++j)
      out[(size_t)(by * 64 + tr * 4 + i) * N_TOT + bx * 64 + tc * 4 + j] = c[i][j];
}

extern "C" void kernel_launch(void* const* d_in, const int* in_sizes, int n_in,
                              void* d_out, int out_size, void* d_ws, size_t ws_size,
                              hipStream_t stream) {
  const float* x      = (const float*)d_in[0];   // (4,2048,4096) f32
  const float* weight = (const float*)d_in[1];   // (4096,4096)   f32
  const float* mora   = (const float*)d_in[2];   // (2048,2048)   f32
  const float* dora   = (const float*)d_in[3];   // (1,4096)      f32
  float* out = (float*)d_out;                    // (4,2048,4096) f32

  char* ws = (char*)d_ws;
  float* partials = (float*)ws;                         // 512 KB
  float* scale    = (float*)(ws + (512 << 10));         // 16 KB
  const size_t OFF_W = (size_t)1 << 20;
  unsigned short* wbuf = (unsigned short*)(ws + OFF_W);                              // 32 MB
  unsigned short* xbuf = (unsigned short*)(ws + OFF_W + (size_t)N_TOT * K_TOT * 2);  // 64 MB
  const size_t NEED = OFF_W + (size_t)N_TOT * K_TOT * 2 + (size_t)M_TOT * K_TOT * 2;

  dim3 b256(256);
  colnorm_partial_k<<<dim3(16, 32), b256, 0, stream>>>(weight, mora, partials);
  scale_k<<<16, b256, 0, stream>>>(partials, dora, scale);

  if (ws_size >= NEED) {
    pack_w_k<<<(N_TOT * K_TOT) / (256 * 8), b256, 0, stream>>>(weight, mora, scale, wbuf);
    pack_x_k<<<(M_TOT * K_TOT) / (256 * 8), b256, 0, stream>>>(x, xbuf);
    gemm_bf16_k<<<(M_TOT / BM) * (N_TOT / BN), 512, 0, stream>>>(xbuf, wbuf, out);
  } else {
    gemm_fb_k<<<dim3(N_TOT / 64, M_TOT / 64), b256, 0, stream>>>(x, weight, mora, scale, out);
  }
}

// Round 4
// 324.772 us; speedup vs baseline: 1.3787x; 1.0356x over previous
//
#include <hip/hip_runtime.h>
#include <stdint.h>

#define M_TOT 8192
#define N_TOT 4096
#define K_TOT 4096
#define BM 256
#define BN 256
#define BK 32
#define NT (K_TOT / BK)   // 128 K-tiles

typedef short  s16x8 __attribute__((ext_vector_type(8)));
typedef unsigned short u16x8 __attribute__((ext_vector_type(8)));
typedef float  f32x4 __attribute__((ext_vector_type(4)));

__device__ __forceinline__ unsigned short f32_to_bf16(float f) {
  union { float f; unsigned u; } v; v.f = f;
  unsigned r = v.u + 0x7FFFu + ((v.u >> 16) & 1u);   // RNE
  return (unsigned short)(r >> 16);
}

__device__ __forceinline__ void gload_lds16(void* lds, const void* g) {
  __builtin_amdgcn_global_load_lds(
      (const __attribute__((address_space(1))) unsigned int*)g,
      (__attribute__((address_space(3))) unsigned int*)lds,
      16, 0, 0);
}

// ---- Prep 1: partial column sums of squares of (weight + tiled mora) ----
__global__ void colnorm_partial_k(const float* __restrict__ weight,
                                  const float* __restrict__ mora,
                                  float* __restrict__ partials) {
  int d = blockIdx.x * 256 + threadIdx.x;
  int o0 = blockIdx.y * 128;
  float s = 0.f;
  #pragma unroll 4
  for (int o = o0; o < o0 + 128; ++o) {
    float w = weight[(size_t)o * K_TOT + d] + mora[(size_t)(o >> 1) * 2048 + (d >> 1)];
    s = fmaf(w, w, s);
  }
  partials[blockIdx.y * K_TOT + d] = s;
}

// ---- Prep 2: scale[d] = dora_mag[d] / sqrt(sum) ----
__global__ void scale_k(const float* __restrict__ partials,
                        const float* __restrict__ dora_mag,
                        float* __restrict__ scale) {
  int d = blockIdx.x * 256 + threadIdx.x;
  float s = 0.f;
  #pragma unroll
  for (int c = 0; c < 32; ++c) s += partials[c * K_TOT + d];
  scale[d] = dora_mag[d] / sqrtf(s);
}

// ---- Prep 3: w_bf16[o][d] = bf16((weight + mora_tiled) * scale[d]) ----
__global__ void pack_w_k(const float* __restrict__ weight,
                         const float* __restrict__ mora,
                         const float* __restrict__ scale,
                         unsigned short* __restrict__ wb) {
  size_t idx = ((size_t)blockIdx.x * 256 + threadIdx.x) * 8;
  int o = (int)(idx >> 12);
  int d = (int)(idx & (K_TOT - 1));
  float4 w0 = *(const float4*)(weight + idx);
  float4 w1 = *(const float4*)(weight + idx + 4);
  float4 mv = *(const float4*)(mora + (size_t)(o >> 1) * 2048 + (d >> 1));
  float4 s0 = *(const float4*)(scale + d);
  float4 s1 = *(const float4*)(scale + d + 4);
  u16x8 r;
  r[0] = f32_to_bf16((w0.x + mv.x) * s0.x);
  r[1] = f32_to_bf16((w0.y + mv.x) * s0.y);
  r[2] = f32_to_bf16((w0.z + mv.y) * s0.z);
  r[3] = f32_to_bf16((w0.w + mv.y) * s0.w);
  r[4] = f32_to_bf16((w1.x + mv.z) * s1.x);
  r[5] = f32_to_bf16((w1.y + mv.z) * s1.y);
  r[6] = f32_to_bf16((w1.z + mv.w) * s1.z);
  r[7] = f32_to_bf16((w1.w + mv.w) * s1.w);
  *(u16x8*)(wb + idx) = r;
}

// ---- Prep 4: x -> bf16 ----
__global__ void pack_x_k(const float* __restrict__ x, unsigned short* __restrict__ xb) {
  size_t idx = ((size_t)blockIdx.x * 256 + threadIdx.x) * 8;
  float4 v0 = *(const float4*)(x + idx);
  float4 v1 = *(const float4*)(x + idx + 4);
  u16x8 r;
  r[0] = f32_to_bf16(v0.x); r[1] = f32_to_bf16(v0.y);
  r[2] = f32_to_bf16(v0.z); r[3] = f32_to_bf16(v0.w);
  r[4] = f32_to_bf16(v1.x); r[5] = f32_to_bf16(v1.y);
  r[6] = f32_to_bf16(v1.z); r[7] = f32_to_bf16(v1.w);
  *(u16x8*)(xb + idx) = r;
}

// ---- Main GEMM: 256x256 tile, BK=32, 8 waves (2x4), ring-4 LDS,
// 4 fine phases per 2 K-tiles, counted vmcnt, setprio (T3+T4+T5),
// and T2-style XOR swizzle on the K-block index:
//   LDS physical (row, p) holds global (row, p ^ key(row)), key = (row>>1)&3.
// Implemented per rule #21: linear LDS dest + pre-swizzled GLOBAL source
// + same XOR on the ds_read address. Per-16-lane-quarter bank check:
// 8 spans x 2 lanes each -> conflict-free. ----
__global__ void __launch_bounds__(512, 2) gemm_bf16_k(
    const unsigned short* __restrict__ xb,   // [8192][4096]
    const unsigned short* __restrict__ wb,   // [4096][4096]
    float* __restrict__ out) {               // [8192][4096]
  __shared__ short lds[4][2][BM * BK];       // 4 ring x (A,B) x 16KB = 128KB

  const int tid = threadIdx.x;
  const int l   = tid & 63;
  const int wid = tid >> 6;
  const int wm  = wid >> 2;                  // 0..1 -> M rows wm*128
  const int wn  = wid & 3;                   // 0..3 -> N cols wn*64

  // XCD-aware bijective swizzle (nwg=512, divisible by 8)
  const int orig = blockIdx.x;
  const int swz  = (orig & 7) * (512 >> 3) + (orig >> 3);
  const int by = swz >> 4;                   // 0..31
  const int bx = swz & 15;                   // 0..15

  const unsigned short* ag = xb + (size_t)(by * BM) * K_TOT;
  const unsigned short* bg = wb + (size_t)(bx * BN) * K_TOT;

  // staging: 1024 16B-chunks per operand K-tile; chunk c -> LDS offset c*16B
  // (linear). Global source: row = c>>2, K-block = (c&3) ^ key(row).
  const int c0 = tid, c1 = 512 + tid;
  const int r0s = c0 >> 2, r1s = c1 >> 2;
  const int g0 = (c0 & 3) ^ ((r0s >> 1) & 3);
  const int g1 = (c1 & 3) ^ ((r1s >> 1) & 3);
  const unsigned short* gA0 = ag + (size_t)r0s * K_TOT + g0 * 8;
  const unsigned short* gA1 = ag + (size_t)r1s * K_TOT + g1 * 8;
  const unsigned short* gB0 = bg + (size_t)r0s * K_TOT + g0 * 8;
  const unsigned short* gB1 = bg + (size_t)r1s * K_TOT + g1 * 8;
  const int lo0 = (tid & ~63) * 8;           // wave-uniform LDS base (shorts)
  const int lo1 = lo0 + 512 * 8;

  const int lrow = l & 15;
  const int key  = (lrow >> 1) & 3;          // invariant under row+16 steps
  const int blk  = ((l >> 4) ^ key) * 8;     // swizzled K-block (shorts)
  const int aoffb = (wm * 128 + lrow) * BK + blk;
  const int boffb = (wn * 64  + lrow) * BK + blk;

  s16x8 afr[4], bfr[4];
  f32x4 acc[8][4] = {};

#define STG_A(t) { short* p = &lds[(t) & 3][0][0]; \
    gload_lds16(p + lo0, gA0 + (size_t)(t) * BK); \
    gload_lds16(p + lo1, gA1 + (size_t)(t) * BK); }
#define STG_B(t) { short* p = &lds[(t) & 3][1][0]; \
    gload_lds16(p + lo0, gB0 + (size_t)(t) * BK); \
    gload_lds16(p + lo1, gB1 + (size_t)(t) * BK); }
#define DS_A(t, mb) { const short* p = &lds[(t) & 3][0][aoffb + (mb) * 16 * BK]; \
    afr[0] = *(const s16x8*)(p);               afr[1] = *(const s16x8*)(p + 16 * BK); \
    afr[2] = *(const s16x8*)(p + 32 * BK);     afr[3] = *(const s16x8*)(p + 48 * BK); }
#define DS_B(t) { const short* p = &lds[(t) & 3][1][boffb]; \
    bfr[0] = *(const s16x8*)(p);               bfr[1] = *(const s16x8*)(p + 16 * BK); \
    bfr[2] = *(const s16x8*)(p + 32 * BK);     bfr[3] = *(const s16x8*)(p + 48 * BK); }
#define BAR() __builtin_amdgcn_s_barrier()
#define LGKM0() asm volatile("s_waitcnt lgkmcnt(0)" ::: "memory")
#define VM8() asm volatile("s_waitcnt vmcnt(8)" ::: "memory")
#define VM4() asm volatile("s_waitcnt vmcnt(4)" ::: "memory")
#define VM0() asm volatile("s_waitcnt vmcnt(0)" ::: "memory")
#define MM(mb) { __builtin_amdgcn_s_setprio(1); \
    _Pragma("unroll") for (int mm = 0; mm < 4; ++mm) { \
      _Pragma("unroll") for (int nn = 0; nn < 4; ++nn) \
        acc[(mb) + mm][nn] = __builtin_amdgcn_mfma_f32_16x16x32_bf16(afr[mm], bfr[nn], acc[(mb) + mm][nn], 0, 0, 0); } \
    __builtin_amdgcn_s_setprio(0); }

  // prologue: 3 K-tiles staged (12 loads/thread in flight)
  STG_A(0); STG_B(0); STG_A(1); STG_B(1); STG_A(2); STG_B(2);
  VM8(); BAR();                               // tile 0 complete

  #pragma unroll 1
  for (int t = 0; t < NT - 4; t += 2) {
    // phase 1: tile t, quadrant m0-3
    DS_A(t, 0); DS_B(t);
    STG_A(t + 3);
    BAR(); LGKM0(); MM(0); BAR();
    // phase 2: tile t, quadrant m4-7 (bfr reused)
    DS_A(t, 4);
    STG_B(t + 3);
    BAR(); LGKM0(); MM(4);
    VM8(); BAR();                             // tile t+1 complete
    // phase 3: tile t+1, quadrant m0-3
    DS_A(t + 1, 0); DS_B(t + 1);
    STG_A(t + 4);
    BAR(); LGKM0(); MM(0); BAR();
    // phase 4: tile t+1, quadrant m4-7
    DS_A(t + 1, 4);
    STG_B(t + 4);
    BAR(); LGKM0(); MM(4);
    VM8(); BAR();                             // tile t+2 complete
  }

  // peel tiles 124,125 (stage only tile 127)
  DS_A(124, 0); DS_B(124);
  STG_A(127);
  BAR(); LGKM0(); MM(0); BAR();
  DS_A(124, 4);
  STG_B(127);
  BAR(); LGKM0(); MM(4);
  VM8(); BAR();                               // tile 125 complete
  DS_A(125, 0); DS_B(125);
  BAR(); LGKM0(); MM(0); BAR();
  DS_A(125, 4);
  BAR(); LGKM0(); MM(4);
  VM4(); BAR();                               // tile 126 complete
  // peel tiles 126,127 (no staging)
  DS_A(126, 0); DS_B(126);
  BAR(); LGKM0(); MM(0); BAR();
  DS_A(126, 4);
  BAR(); LGKM0(); MM(4);
  VM0(); BAR();                               // tile 127 complete
  DS_A(127, 0); DS_B(127);
  BAR(); LGKM0(); MM(0); BAR();
  DS_A(127, 4);
  LGKM0(); MM(4);

#undef STG_A
#undef STG_B
#undef DS_A
#undef DS_B
#undef MM

  // C/D layout (verified R1/R2): col = lane&15, row = (lane>>4)*4 + reg
  const int row0 = by * BM + wm * 128 + (l >> 4) * 4;
  const int col0 = bx * BN + wn * 64 + lrow;
  #pragma unroll
  for (int m = 0; m < 8; ++m)
    #pragma unroll
    for (int n = 0; n < 4; ++n) {
      #pragma unroll
      for (int j = 0; j < 4; ++j)
        out[(size_t)(row0 + m * 16 + j) * N_TOT + col0 + n * 16] = acc[m][n][j];
    }
}

// ---- Fallback fp32 GEMM (only if ws too small for bf16 copies) ----
__global__ void gemm_fb_k(const float* __restrict__ x, const float* __restrict__ weight,
                          const float* __restrict__ mora, const float* __restrict__ scale,
                          float* __restrict__ out) {
  __shared__ float As[64][17];
  __shared__ float Bs[64][17];
  int t = threadIdx.x;
  int bx = blockIdx.x, by = blockIdx.y;
  int tr = t >> 4, tc = t & 15;
  float c[4][4] = {};
  for (int kt = 0; kt < K_TOT; kt += 16) {
    #pragma unroll
    for (int r = 0; r < 4; ++r) {
      int idx = r * 256 + t;
      int row = idx >> 4, col = idx & 15;
      As[row][col] = x[(size_t)(by * 64 + row) * K_TOT + kt + col];
      int o = bx * 64 + row, d = kt + col;
      Bs[row][col] = (weight[(size_t)o * K_TOT + d] + mora[(size_t)(o >> 1) * 2048 + (d >> 1)]) * scale[d];
    }
    __syncthreads();
    #pragma unroll
    for (int k = 0; k < 16; ++k) {
      float av[4], bv[4];
      #pragma unroll
      for (int i = 0; i < 4; ++i) av[i] = As[tr * 4 + i][k];
      #pragma unroll
      for (int j = 0; j < 4; ++j) bv[j] = Bs[tc * 4 + j][k];
      #pragma unroll
      for (int i = 0; i < 4; ++i)
        #pragma unroll
        for (int j = 0; j < 4; ++j)
          c[i][j] = fmaf(av[i], bv[j], c[i][j]);
    }
    __syncthreads();
  }
  #pragma unroll
  for (int i = 0; i < 4; ++i)
    #pragma unroll
    for (int j = 0; j < 4; ++j)
      out[(size_t)(by * 64 + tr * 4 + i) * N_TOT + bx * 64 + tc * 4 + j] = c[i][j];
}

extern "C" void kernel_launch(void* const* d_in, const int* in_sizes, int n_in,
                              void* d_out, int out_size, void* d_ws, size_t ws_size,
                              hipStream_t stream) {
  const float* x      = (const float*)d_in[0];   // (4,2048,4096) f32
  const float* weight = (const float*)d_in[1];   // (4096,4096)   f32
  const float* mora   = (const float*)d_in[2];   // (2048,2048)   f32
  const float* dora   = (const float*)d_in[3];   // (1,4096)      f32
  float* out = (float*)d_out;                    // (4,2048,4096) f32

  char* ws = (char*)d_ws;
  float* partials = (float*)ws;                         // 512 KB
  float* scale    = (float*)(ws + (512 << 10));         // 16 KB
  const size_t OFF_W = (size_t)1 << 20;
  unsigned short* wbuf = (unsigned short*)(ws + OFF_W);                              // 32 MB
  unsigned short* xbuf = (unsigned short*)(ws + OFF_W + (size_t)N_TOT * K_TOT * 2);  // 64 MB
  const size_t NEED = OFF_W + (size_t)N_TOT * K_TOT * 2 + (size_t)M_TOT * K_TOT * 2;

  dim3 b256(256);
  colnorm_partial_k<<<dim3(16, 32), b256, 0, stream>>>(weight, mora, partials);
  scale_k<<<16, b256, 0, stream>>>(partials, dora, scale);

  if (ws_size >= NEED) {
    pack_w_k<<<(N_TOT * K_TOT) / (256 * 8), b256, 0, stream>>>(weight, mora, scale, wbuf);
    pack_x_k<<<(M_TOT * K_TOT) / (256 * 8), b256, 0, stream>>>(x, xbuf);
    gemm_bf16_k<<<(M_TOT / BM) * (N_TOT / BN), 512, 0, stream>>>(xbuf, wbuf, out);
  } else {
    gemm_fb_k<<<dim3(N_TOT / 64, M_TOT / 64), b256, 0, stream>>>(x, weight, mora, scale, out);
  }
}

// Round 5
// 323.603 us; speedup vs baseline: 1.3836x; 1.0036x over previous
//
#include <hip/hip_runtime.h>
#include <stdint.h>

#define M_TOT 8192
#define N_TOT 4096
#define K_TOT 4096
#define BM 256
#define BN 256
#define BK 32
#define NT (K_TOT / BK)   // 128 K-tiles

typedef short  s16x8 __attribute__((ext_vector_type(8)));
typedef unsigned short u16x8 __attribute__((ext_vector_type(8)));
typedef float  f32x4 __attribute__((ext_vector_type(4)));

__device__ __forceinline__ unsigned short f32_to_bf16(float f) {
  union { float f; unsigned u; } v; v.f = f;
  unsigned r = v.u + 0x7FFFu + ((v.u >> 16) & 1u);   // RNE
  return (unsigned short)(r >> 16);
}

__device__ __forceinline__ void gload_lds16(void* lds, const void* g) {
  __builtin_amdgcn_global_load_lds(
      (const __attribute__((address_space(1))) unsigned int*)g,
      (__attribute__((address_space(3))) unsigned int*)lds,
      16, 0, 0);
}

// ---- Prep 1: partial column sums of squares of (weight + tiled mora) ----
__global__ void colnorm_partial_k(const float* __restrict__ weight,
                                  const float* __restrict__ mora,
                                  float* __restrict__ partials) {
  int d = blockIdx.x * 256 + threadIdx.x;
  int o0 = blockIdx.y * 128;
  float s = 0.f;
  #pragma unroll 4
  for (int o = o0; o < o0 + 128; ++o) {
    float w = weight[(size_t)o * K_TOT + d] + mora[(size_t)(o >> 1) * 2048 + (d >> 1)];
    s = fmaf(w, w, s);
  }
  partials[blockIdx.y * K_TOT + d] = s;
}

// ---- Prep 2: scale[d] = dora_mag[d] / sqrt(sum) ----
__global__ void scale_k(const float* __restrict__ partials,
                        const float* __restrict__ dora_mag,
                        float* __restrict__ scale) {
  int d = blockIdx.x * 256 + threadIdx.x;
  float s = 0.f;
  #pragma unroll
  for (int c = 0; c < 32; ++c) s += partials[c * K_TOT + d];
  scale[d] = dora_mag[d] / sqrtf(s);
}

// ---- Prep 3: w_bf16[o][d] = bf16((weight + mora_tiled) * scale[d]) ----
__global__ void pack_w_k(const float* __restrict__ weight,
                         const float* __restrict__ mora,
                         const float* __restrict__ scale,
                         unsigned short* __restrict__ wb) {
  size_t idx = ((size_t)blockIdx.x * 256 + threadIdx.x) * 8;
  int o = (int)(idx >> 12);
  int d = (int)(idx & (K_TOT - 1));
  float4 w0 = *(const float4*)(weight + idx);
  float4 w1 = *(const float4*)(weight + idx + 4);
  float4 mv = *(const float4*)(mora + (size_t)(o >> 1) * 2048 + (d >> 1));
  float4 s0 = *(const float4*)(scale + d);
  float4 s1 = *(const float4*)(scale + d + 4);
  u16x8 r;
  r[0] = f32_to_bf16((w0.x + mv.x) * s0.x);
  r[1] = f32_to_bf16((w0.y + mv.x) * s0.y);
  r[2] = f32_to_bf16((w0.z + mv.y) * s0.z);
  r[3] = f32_to_bf16((w0.w + mv.y) * s0.w);
  r[4] = f32_to_bf16((w1.x + mv.z) * s1.x);
  r[5] = f32_to_bf16((w1.y + mv.z) * s1.y);
  r[6] = f32_to_bf16((w1.z + mv.w) * s1.z);
  r[7] = f32_to_bf16((w1.w + mv.w) * s1.w);
  *(u16x8*)(wb + idx) = r;
}

// ---- Prep 4: x -> bf16 ----
__global__ void pack_x_k(const float* __restrict__ x, unsigned short* __restrict__ xb) {
  size_t idx = ((size_t)blockIdx.x * 256 + threadIdx.x) * 8;
  float4 v0 = *(const float4*)(x + idx);
  float4 v1 = *(const float4*)(x + idx + 4);
  u16x8 r;
  r[0] = f32_to_bf16(v0.x); r[1] = f32_to_bf16(v0.y);
  r[2] = f32_to_bf16(v0.z); r[3] = f32_to_bf16(v0.w);
  r[4] = f32_to_bf16(v1.x); r[5] = f32_to_bf16(v1.y);
  r[6] = f32_to_bf16(v1.z); r[7] = f32_to_bf16(v1.w);
  *(u16x8*)(xb + idx) = r;
}

// ---- Main GEMM: 256x256 tile, BK=32, 8 waves (2x4), ring-4 LDS,
// REGISTER double-buffered fragments: read tile t+1's frags while issuing
// tile t's MFMAs (LDS pipe || matrix pipe). One barrier per K-tile.
// Counted vmcnt (4 loads/tile, 3 tiles in flight, VM8 steady state).
// LGKM0 before each barrier makes ring-4 buffer reuse formally race-free:
// all waves' reads of tile u are drained before BAR(u); STG(u+3) overwrites
// tile u-1's buffer and is issued after BAR(u-1). XOR bank swizzle (R4,
// conflicts==0) unchanged. ----
__global__ void __launch_bounds__(512, 2) gemm_bf16_k(
    const unsigned short* __restrict__ xb,   // [8192][4096]
    const unsigned short* __restrict__ wb,   // [4096][4096]
    float* __restrict__ out) {               // [8192][4096]
  __shared__ short lds[4][2][BM * BK];       // 4 ring x (A,B) x 16KB = 128KB

  const int tid = threadIdx.x;
  const int l   = tid & 63;
  const int wid = tid >> 6;
  const int wm  = wid >> 2;                  // 0..1 -> M rows wm*128
  const int wn  = wid & 3;                   // 0..3 -> N cols wn*64

  // XCD-aware bijective swizzle (nwg=512, divisible by 8)
  const int orig = blockIdx.x;
  const int swz  = (orig & 7) * (512 >> 3) + (orig >> 3);
  const int by = swz >> 4;                   // 0..31
  const int bx = swz & 15;                   // 0..15

  const unsigned short* ag = xb + (size_t)(by * BM) * K_TOT;
  const unsigned short* bg = wb + (size_t)(bx * BN) * K_TOT;

  // staging: 1024 16B-chunks per operand K-tile; chunk c -> LDS offset c*16B
  // (linear). Global source: row = c>>2, K-block = (c&3) ^ key(row).
  const int c0 = tid, c1 = 512 + tid;
  const int r0s = c0 >> 2, r1s = c1 >> 2;
  const int g0 = (c0 & 3) ^ ((r0s >> 1) & 3);
  const int g1 = (c1 & 3) ^ ((r1s >> 1) & 3);
  const unsigned short* gA0 = ag + (size_t)r0s * K_TOT + g0 * 8;
  const unsigned short* gA1 = ag + (size_t)r1s * K_TOT + g1 * 8;
  const unsigned short* gB0 = bg + (size_t)r0s * K_TOT + g0 * 8;
  const unsigned short* gB1 = bg + (size_t)r1s * K_TOT + g1 * 8;
  const int lo0 = (tid & ~63) * 8;           // wave-uniform LDS base (shorts)
  const int lo1 = lo0 + 512 * 8;

  const int lrow = l & 15;
  const int key  = (lrow >> 1) & 3;          // invariant under row+16 steps
  const int blk  = ((l >> 4) ^ key) * 8;     // swizzled K-block (shorts)
  const int aoffb = (wm * 128 + lrow) * BK + blk;
  const int boffb = (wn * 64  + lrow) * BK + blk;

  s16x8 af0[8], bf0[4], af1[8], bf1[4];      // double-buffered fragment sets
  f32x4 acc[8][4] = {};

#define STG(t) { \
    short* pa = &lds[(t) & 3][0][0]; short* pb = &lds[(t) & 3][1][0]; \
    gload_lds16(pa + lo0, gA0 + (size_t)(t) * BK); \
    gload_lds16(pb + lo0, gB0 + (size_t)(t) * BK); \
    gload_lds16(pa + lo1, gA1 + (size_t)(t) * BK); \
    gload_lds16(pb + lo1, gB1 + (size_t)(t) * BK); }
#define READF(t, af, bf) { \
    const short* pa = &lds[(t) & 3][0][aoffb]; \
    const short* pb = &lds[(t) & 3][1][boffb]; \
    _Pragma("unroll") for (int i = 0; i < 4; ++i) bf[i] = *(const s16x8*)(pb + i * 16 * BK); \
    _Pragma("unroll") for (int i = 0; i < 8; ++i) af[i] = *(const s16x8*)(pa + i * 16 * BK); }
#define MMAF(af, bf) { __builtin_amdgcn_s_setprio(1); \
    _Pragma("unroll") for (int mm = 0; mm < 8; ++mm) { \
      _Pragma("unroll") for (int nn = 0; nn < 4; ++nn) \
        acc[mm][nn] = __builtin_amdgcn_mfma_f32_16x16x32_bf16(af[mm], bf[nn], acc[mm][nn], 0, 0, 0); } \
    __builtin_amdgcn_s_setprio(0); }
#define BAR() __builtin_amdgcn_s_barrier()
#define SB0() __builtin_amdgcn_sched_barrier(0)
#define LGKM0() asm volatile("s_waitcnt lgkmcnt(0)" ::: "memory")
#define VM8() asm volatile("s_waitcnt vmcnt(8)" ::: "memory")
#define VM4() asm volatile("s_waitcnt vmcnt(4)" ::: "memory")
#define VM0() asm volatile("s_waitcnt vmcnt(0)" ::: "memory")

  // prologue: stage 3 K-tiles (12 loads/thread in flight)
  STG(0); STG(1); STG(2);
  VM8(); BAR(); SB0();                        // tile 0 complete (all waves)
  READF(0, af0, bf0);

  #pragma unroll 1
  for (int t = 0; t < NT - 4; t += 2) {
    // even: compute t (set0), read t+1 into set1
    STG(t + 3);
    VM8(); LGKM0(); BAR(); SB0();             // tile t+1 staged; reads<=t drained
    READF(t + 1, af1, bf1);
    SB0();
    MMAF(af0, bf0);                           // overlaps set1 reads in LDS pipe
    // odd: compute t+1 (set1), read t+2 into set0
    STG(t + 4);
    VM8(); LGKM0(); BAR(); SB0();
    READF(t + 2, af0, bf0);
    SB0();
    MMAF(af1, bf1);
  }

  // peel: tiles 124..127 (staged 0..126 so far; set0 holds tile 124)
  STG(127);
  VM8(); LGKM0(); BAR(); SB0();               // tile 125 staged
  READF(125, af1, bf1);
  SB0();
  MMAF(af0, bf0);                             // tile 124
  VM4(); LGKM0(); BAR(); SB0();               // tile 126 staged
  READF(126, af0, bf0);
  SB0();
  MMAF(af1, bf1);                             // tile 125
  VM0(); LGKM0(); BAR(); SB0();               // tile 127 staged
  READF(127, af1, bf1);
  SB0();
  MMAF(af0, bf0);                             // tile 126
  LGKM0();
  MMAF(af1, bf1);                             // tile 127

#undef STG
#undef READF
#undef MMAF

  // C/D layout (verified R1/R2): col = lane&15, row = (lane>>4)*4 + reg
  const int row0 = by * BM + wm * 128 + (l >> 4) * 4;
  const int col0 = bx * BN + wn * 64 + lrow;
  #pragma unroll
  for (int m = 0; m < 8; ++m)
    #pragma unroll
    for (int n = 0; n < 4; ++n) {
      #pragma unroll
      for (int j = 0; j < 4; ++j)
        out[(size_t)(row0 + m * 16 + j) * N_TOT + col0 + n * 16] = acc[m][n][j];
    }
}

// ---- Fallback fp32 GEMM (only if ws too small for bf16 copies) ----
__global__ void gemm_fb_k(const float* __restrict__ x, const float* __restrict__ weight,
                          const float* __restrict__ mora, const float* __restrict__ scale,
                          float* __restrict__ out) {
  __shared__ float As[64][17];
  __shared__ float Bs[64][17];
  int t = threadIdx.x;
  int bx = blockIdx.x, by = blockIdx.y;
  int tr = t >> 4, tc = t & 15;
  float c[4][4] = {};
  for (int kt = 0; kt < K_TOT; kt += 16) {
    #pragma unroll
    for (int r = 0; r < 4; ++r) {
      int idx = r * 256 + t;
      int row = idx >> 4, col = idx & 15;
      As[row][col] = x[(size_t)(by * 64 + row) * K_TOT + kt + col];
      int o = bx * 64 + row, d = kt + col;
      Bs[row][col] = (weight[(size_t)o * K_TOT + d] + mora[(size_t)(o >> 1) * 2048 + (d >> 1)]) * scale[d];
    }
    __syncthreads();
    #pragma unroll
    for (int k = 0; k < 16; ++k) {
      float av[4], bv[4];
      #pragma unroll
      for (int i = 0; i < 4; ++i) av[i] = As[tr * 4 + i][k];
      #pragma unroll
      for (int j = 0; j < 4; ++j) bv[j] = Bs[tc * 4 + j][k];
      #pragma unroll
      for (int i = 0; i < 4; ++i)
        #pragma unroll
        for (int j = 0; j < 4; ++j)
          c[i][j] = fmaf(av[i], bv[j], c[i][j]);
    }
    __syncthreads();
  }
  #pragma unroll
  for (int i = 0; i < 4; ++i)
    #pragma unroll
    for (int j = 0; j < 4; ++j)
      out[(size_t)(by * 64 + tr * 4 + i) * N_TOT + bx * 64 + tc * 4 + j] = c[i][j];
}

extern "C" void kernel_launch(void* const* d_in, const int* in_sizes, int n_in,
                              void* d_out, int out_size, void* d_ws, size_t ws_size,
                              hipStream_t stream) {
  const float* x      = (const float*)d_in[0];   // (4,2048,4096) f32
  const float* weight = (const float*)d_in[1];   // (4096,4096)   f32
  const float* mora   = (const float*)d_in[2];   // (2048,2048)   f32
  const float* dora   = (const float*)d_in[3];   // (1,4096)      f32
  float* out = (float*)d_out;                    // (4,2048,4096) f32

  char* ws = (char*)d_ws;
  float* partials = (float*)ws;                         // 512 KB
  float* scale    = (float*)(ws + (512 << 10));         // 16 KB
  const size_t OFF_W = (size_t)1 << 20;
  unsigned short* wbuf = (unsigned short*)(ws + OFF_W);                              // 32 MB
  unsigned short* xbuf = (unsigned short*)(ws + OFF_W + (size_t)N_TOT * K_TOT * 2);  // 64 MB
  const size_t NEED = OFF_W + (size_t)N_TOT * K_TOT * 2 + (size_t)M_TOT * K_TOT * 2;

  dim3 b256(256);
  colnorm_partial_k<<<dim3(16, 32), b256, 0, stream>>>(weight, mora, partials);
  scale_k<<<16, b256, 0, stream>>>(partials, dora, scale);

  if (ws_size >= NEED) {
    pack_w_k<<<(N_TOT * K_TOT) / (256 * 8), b256, 0, stream>>>(weight, mora, scale, wbuf);
    pack_x_k<<<(M_TOT * K_TOT) / (256 * 8), b256, 0, stream>>>(x, xbuf);
    gemm_bf16_k<<<(M_TOT / BM) * (N_TOT / BN), 512, 0, stream>>>(xbuf, wbuf, out);
  } else {
    gemm_fb_k<<<dim3(N_TOT / 64, M_TOT / 64), b256, 0, stream>>>(x, weight, mora, scale, out);
  }
}

// Round 6
// 307.532 us; speedup vs baseline: 1.4559x; 1.0523x over previous
//
#include <hip/hip_runtime.h>
#include <stdint.h>

#define M_TOT 8192
#define N_TOT 4096
#define K_TOT 4096
#define BM 256
#define BN 256
#define BK 64
#define NIT (K_TOT / (2 * BK))   // 32 iters, 2 K-tiles each

typedef short  s16x8 __attribute__((ext_vector_type(8)));
typedef unsigned short u16x8 __attribute__((ext_vector_type(8)));
typedef float  f32x4 __attribute__((ext_vector_type(4)));

__device__ __forceinline__ unsigned short f32_to_bf16(float f) {
  union { float f; unsigned u; } v; v.f = f;
  unsigned r = v.u + 0x7FFFu + ((v.u >> 16) & 1u);   // RNE
  return (unsigned short)(r >> 16);
}

__device__ __forceinline__ void gload_lds16(void* lds, const void* g) {
  __builtin_amdgcn_global_load_lds(
      (const __attribute__((address_space(1))) unsigned int*)g,
      (__attribute__((address_space(3))) unsigned int*)lds,
      16, 0, 0);
}

// ---- Prep 1: partial column sums of squares of (weight + tiled mora) ----
__global__ void colnorm_partial_k(const float* __restrict__ weight,
                                  const float* __restrict__ mora,
                                  float* __restrict__ partials) {
  int d = blockIdx.x * 256 + threadIdx.x;
  int o0 = blockIdx.y * 128;
  float s = 0.f;
  #pragma unroll 4
  for (int o = o0; o < o0 + 128; ++o) {
    float w = weight[(size_t)o * K_TOT + d] + mora[(size_t)(o >> 1) * 2048 + (d >> 1)];
    s = fmaf(w, w, s);
  }
  partials[blockIdx.y * K_TOT + d] = s;
}

// ---- Prep 2: scale[d] = dora_mag[d] / sqrt(sum) ----
__global__ void scale_k(const float* __restrict__ partials,
                        const float* __restrict__ dora_mag,
                        float* __restrict__ scale) {
  int d = blockIdx.x * 256 + threadIdx.x;
  float s = 0.f;
  #pragma unroll
  for (int c = 0; c < 32; ++c) s += partials[c * K_TOT + d];
  scale[d] = dora_mag[d] / sqrtf(s);
}

// ---- Prep 3: w_bf16[o][d] = bf16((weight + mora_tiled) * scale[d]) ----
__global__ void pack_w_k(const float* __restrict__ weight,
                         const float* __restrict__ mora,
                         const float* __restrict__ scale,
                         unsigned short* __restrict__ wb) {
  size_t idx = ((size_t)blockIdx.x * 256 + threadIdx.x) * 8;
  int o = (int)(idx >> 12);
  int d = (int)(idx & (K_TOT - 1));
  float4 w0 = *(const float4*)(weight + idx);
  float4 w1 = *(const float4*)(weight + idx + 4);
  float4 mv = *(const float4*)(mora + (size_t)(o >> 1) * 2048 + (d >> 1));
  float4 s0 = *(const float4*)(scale + d);
  float4 s1 = *(const float4*)(scale + d + 4);
  u16x8 r;
  r[0] = f32_to_bf16((w0.x + mv.x) * s0.x);
  r[1] = f32_to_bf16((w0.y + mv.x) * s0.y);
  r[2] = f32_to_bf16((w0.z + mv.y) * s0.z);
  r[3] = f32_to_bf16((w0.w + mv.y) * s0.w);
  r[4] = f32_to_bf16((w1.x + mv.z) * s1.x);
  r[5] = f32_to_bf16((w1.y + mv.z) * s1.y);
  r[6] = f32_to_bf16((w1.z + mv.w) * s1.z);
  r[7] = f32_to_bf16((w1.w + mv.w) * s1.w);
  *(u16x8*)(wb + idx) = r;
}

// ---- Prep 4: x -> bf16 ----
__global__ void pack_x_k(const float* __restrict__ x, unsigned short* __restrict__ xb) {
  size_t idx = ((size_t)blockIdx.x * 256 + threadIdx.x) * 8;
  float4 v0 = *(const float4*)(x + idx);
  float4 v1 = *(const float4*)(x + idx + 4);
  u16x8 r;
  r[0] = f32_to_bf16(v0.x); r[1] = f32_to_bf16(v0.y);
  r[2] = f32_to_bf16(v0.z); r[3] = f32_to_bf16(v0.w);
  r[4] = f32_to_bf16(v1.x); r[5] = f32_to_bf16(v1.y);
  r[6] = f32_to_bf16(v1.z); r[7] = f32_to_bf16(v1.w);
  *(u16x8*)(xb + idx) = r;
}

// ---- Main GEMM: m201 8-phase template port. 256x256, BK=64, 8 waves (2x4),
// dbuf LDS (tile parity), per-phase {ds_read || half-tile stage || 16-MFMA
// quadrant}, counted vmcnt(2) at phases 4/8, setprio, XOR swizzle
// (phys_kblk = kblk ^ (row&7), both-sides involution). ----
__global__ void __launch_bounds__(512, 2) gemm_bf16_k(
    const unsigned short* __restrict__ xb,   // [8192][4096]
    const unsigned short* __restrict__ wb,   // [4096][4096]
    float* __restrict__ out) {               // [8192][4096]
  // [buf][op A=0/B=1][half][128*64] = 8 x 16KB = 128KB
  __shared__ short lds[2][2][2][128 * 64];

  const int tid = threadIdx.x;
  const int l   = tid & 63;
  const int wid = tid >> 6;
  const int wm  = wid >> 2;                  // 0..1 -> A half / M rows wm*128
  const int wn  = wid & 3;                   // 0..3 -> N cols wn*64
  const int wnh = wn >> 1;                   // B half

  // XCD-aware bijective swizzle (nwg=512, divisible by 8)
  const int orig = blockIdx.x;
  const int swz  = (orig & 7) * (512 >> 3) + (orig >> 3);
  const int by = swz >> 4;                   // 0..31
  const int bx = swz & 15;                   // 0..15

  const unsigned short* ag = xb + (size_t)(by * BM) * K_TOT;
  const unsigned short* bg = wb + (size_t)(bx * BN) * K_TOT;

  // Staging: half-tile = 128 rows x 64 cols (16KB) = 1024 chunks of 16B;
  // thread handles chunks tid and tid+512. LDS dest linear (chunk c -> c*16B);
  // global source pre-swizzled: kblk_src = (c&7) ^ ((c>>3)&7).
  const int row0 = tid >> 3;
  const int kb0  = (tid & 7) ^ (row0 & 7);   // (row+64)&7 == row&7 -> same for chunk 2
  const int off0 = row0 * K_TOT + kb0 * 8;
  const int off1 = off0 + 64 * K_TOT;
  const int ldst = (tid & ~63) * 8;          // wave-uniform LDS base (shorts)

  // Fragment read addressing: row_local = m*16+lrow (A) / (wn&1)*64+n*16+lrow (B);
  // read kblk phys = (kh*4 + lq) ^ (lrow&7)  [key invariant under +16/+64 rows]
  const int lrow = l & 15;
  const int lq   = l >> 4;
  const int key  = lrow & 7;
  const int ab0  = lrow * 64 + ((lq) ^ key) * 8;        // kh=0
  const int ab1  = lrow * 64 + ((4 + lq) ^ key) * 8;    // kh=1

  s16x8 aA[4][2], bB[4][2];
  f32x4 acc[8][4] = {};

#define STAGE(buf, op, h, t) { \
    short* d = &lds[buf][op][h][0] + ldst; \
    const unsigned short* s = ((op) ? bg : ag) + (size_t)(h) * 128 * K_TOT + (size_t)(t) * BK; \
    gload_lds16(d, s + off0); \
    gload_lds16(d + 4096, s + off1); }
#define DSA(buf, mh) { const short* p = &lds[buf][0][wm][0]; \
    _Pragma("unroll") for (int mm = 0; mm < 4; ++mm) { \
      aA[mm][0] = *(const s16x8*)(p + ((mh) * 4 + mm) * 1024 + ab0); \
      aA[mm][1] = *(const s16x8*)(p + ((mh) * 4 + mm) * 1024 + ab1); } }
#define DSB(buf, nh) { const short* p = &lds[buf][1][wnh][0] + (wn & 1) * 4096; \
    _Pragma("unroll") for (int nn = 0; nn < 2; ++nn) { \
      bB[(nh) * 2 + nn][0] = *(const s16x8*)(p + ((nh) * 2 + nn) * 1024 + ab0); \
      bB[(nh) * 2 + nn][1] = *(const s16x8*)(p + ((nh) * 2 + nn) * 1024 + ab1); } }
#define MMQ(mh, nh) { __builtin_amdgcn_s_setprio(1); \
    _Pragma("unroll") for (int mm = 0; mm < 4; ++mm) \
      _Pragma("unroll") for (int nn = 0; nn < 2; ++nn) \
        _Pragma("unroll") for (int kh = 0; kh < 2; ++kh) \
          acc[(mh) * 4 + mm][(nh) * 2 + nn] = __builtin_amdgcn_mfma_f32_16x16x32_bf16( \
              aA[mm][kh], bB[(nh) * 2 + nn][kh], acc[(mh) * 4 + mm][(nh) * 2 + nn], 0, 0, 0); \
    __builtin_amdgcn_s_setprio(0); }
#define BARm()  asm volatile("s_barrier" ::: "memory")
#define LGKM0() asm volatile("s_waitcnt lgkmcnt(0)" ::: "memory")
#define VM2()   asm volatile("s_waitcnt vmcnt(2)" ::: "memory")
#define VM0()   asm volatile("s_waitcnt vmcnt(0)" ::: "memory")
#define SB0()   __builtin_amdgcn_sched_barrier(0)

  // prologue: tile0 (buf0) all 4 halves + tile1 A-h0 = 10 loads
  STAGE(0, 0, 0, 0); STAGE(0, 0, 1, 0); STAGE(0, 1, 0, 0); STAGE(0, 1, 1, 0);
  STAGE(1, 0, 0, 1);
  VM2(); BARm();                             // buf0 complete; tile1 A-h0 in flight

  #pragma unroll 1
  for (int i = 0; i < NIT - 1; ++i) {
    const int t1 = 2 * i + 1;
    // ph1: buf0 quad(0,0)
    DSA(0, 0); DSB(0, 0); STAGE(1, 0, 1, t1);
    BARm(); LGKM0(); SB0(); MMQ(0, 0); BARm();
    // ph2: buf0 quad(0,1)
    DSB(0, 1); STAGE(1, 1, 0, t1);
    BARm(); LGKM0(); SB0(); MMQ(0, 1); BARm();
    // ph3: buf0 quad(1,0)
    DSA(0, 1); STAGE(1, 1, 1, t1);
    BARm(); LGKM0(); SB0(); MMQ(1, 0); BARm();
    // ph4: buf0 quad(1,1); gate buf1
    STAGE(0, 0, 0, t1 + 1);
    BARm(); LGKM0(); SB0(); MMQ(1, 1); VM2(); BARm();
    // ph5: buf1 quad(0,0)
    DSA(1, 0); DSB(1, 0); STAGE(0, 0, 1, t1 + 1);
    BARm(); LGKM0(); SB0(); MMQ(0, 0); BARm();
    // ph6: buf1 quad(0,1)
    DSB(1, 1); STAGE(0, 1, 0, t1 + 1);
    BARm(); LGKM0(); SB0(); MMQ(0, 1); BARm();
    // ph7: buf1 quad(1,0)
    DSA(1, 1); STAGE(0, 1, 1, t1 + 1);
    BARm(); LGKM0(); SB0(); MMQ(1, 0); BARm();
    // ph8: buf1 quad(1,1); gate buf0 (next iter)
    STAGE(1, 0, 0, t1 + 2);
    BARm(); LGKM0(); SB0(); MMQ(1, 1); VM2(); BARm();
  }

  // peeled last iter (tiles 62,63): stages for tiles >=64 dropped
  DSA(0, 0); DSB(0, 0); STAGE(1, 0, 1, 63);
  BARm(); LGKM0(); SB0(); MMQ(0, 0); BARm();
  DSB(0, 1); STAGE(1, 1, 0, 63);
  BARm(); LGKM0(); SB0(); MMQ(0, 1); BARm();
  DSA(0, 1); STAGE(1, 1, 1, 63);
  BARm(); LGKM0(); SB0(); MMQ(1, 0); BARm();
  BARm(); LGKM0(); SB0(); MMQ(1, 1); VM0(); BARm();
  DSA(1, 0); DSB(1, 0);
  BARm(); LGKM0(); SB0(); MMQ(0, 0); BARm();
  DSB(1, 1);
  BARm(); LGKM0(); SB0(); MMQ(0, 1); BARm();
  DSA(1, 1);
  BARm(); LGKM0(); SB0(); MMQ(1, 0); BARm();
  LGKM0(); SB0(); MMQ(1, 1);

#undef STAGE
#undef DSA
#undef DSB
#undef MMQ

  // C/D layout (verified R1-R5): col = lane&15, row = (lane>>4)*4 + reg
  const int row0o = by * BM + wm * 128 + lq * 4;
  const int col0o = bx * BN + wn * 64 + lrow;
  #pragma unroll
  for (int m = 0; m < 8; ++m)
    #pragma unroll
    for (int n = 0; n < 4; ++n) {
      #pragma unroll
      for (int j = 0; j < 4; ++j)
        out[(size_t)(row0o + m * 16 + j) * N_TOT + col0o + n * 16] = acc[m][n][j];
    }
}

// ---- Fallback fp32 GEMM (only if ws too small for bf16 copies) ----
__global__ void gemm_fb_k(const float* __restrict__ x, const float* __restrict__ weight,
                          const float* __restrict__ mora, const float* __restrict__ scale,
                          float* __restrict__ out) {
  __shared__ float As[64][17];
  __shared__ float Bs[64][17];
  int t = threadIdx.x;
  int bx = blockIdx.x, by = blockIdx.y;
  int tr = t >> 4, tc = t & 15;
  float c[4][4] = {};
  for (int kt = 0; kt < K_TOT; kt += 16) {
    #pragma unroll
    for (int r = 0; r < 4; ++r) {
      int idx = r * 256 + t;
      int row = idx >> 4, col = idx & 15;
      As[row][col] = x[(size_t)(by * 64 + row) * K_TOT + kt + col];
      int o = bx * 64 + row, d = kt + col;
      Bs[row][col] = (weight[(size_t)o * K_TOT + d] + mora[(size_t)(o >> 1) * 2048 + (d >> 1)]) * scale[d];
    }
    __syncthreads();
    #pragma unroll
    for (int k = 0; k < 16; ++k) {
      float av[4], bv[4];
      #pragma unroll
      for (int i = 0; i < 4; ++i) av[i] = As[tr * 4 + i][k];
      #pragma unroll
      for (int j = 0; j < 4; ++j) bv[j] = Bs[tc * 4 + j][k];
      #pragma unroll
      for (int i = 0; i < 4; ++i)
        #pragma unroll
        for (int j = 0; j < 4; ++j)
          c[i][j] = fmaf(av[i], bv[j], c[i][j]);
    }
    __syncthreads();
  }
  #pragma unroll
  for (int i = 0; i < 4; ++i)
    #pragma unroll
    for (int j = 0; j < 4; ++j)
      out[(size_t)(by * 64 + tr * 4 + i) * N_TOT + bx * 64 + tc * 4 + j] = c[i][j];
}

extern "C" void kernel_launch(void* const* d_in, const int* in_sizes, int n_in,
                              void* d_out, int out_size, void* d_ws, size_t ws_size,
                              hipStream_t stream) {
  const float* x      = (const float*)d_in[0];   // (4,2048,4096) f32
  const float* weight = (const float*)d_in[1];   // (4096,4096)   f32
  const float* mora   = (const float*)d_in[2];   // (2048,2048)   f32
  const float* dora   = (const float*)d_in[3];   // (1,4096)      f32
  float* out = (float*)d_out;                    // (4,2048,4096) f32

  char* ws = (char*)d_ws;
  float* partials = (float*)ws;                         // 512 KB
  float* scale    = (float*)(ws + (512 << 10));         // 16 KB
  const size_t OFF_W = (size_t)1 << 20;
  unsigned short* wbuf = (unsigned short*)(ws + OFF_W);                              // 32 MB
  unsigned short* xbuf = (unsigned short*)(ws + OFF_W + (size_t)N_TOT * K_TOT * 2);  // 64 MB
  const size_t NEED = OFF_W + (size_t)N_TOT * K_TOT * 2 + (size_t)M_TOT * K_TOT * 2;

  dim3 b256(256);
  colnorm_partial_k<<<dim3(16, 32), b256, 0, stream>>>(weight, mora, partials);
  scale_k<<<16, b256, 0, stream>>>(partials, dora, scale);

  if (ws_size >= NEED) {
    pack_w_k<<<(N_TOT * K_TOT) / (256 * 8), b256, 0, stream>>>(weight, mora, scale, wbuf);
    pack_x_k<<<(M_TOT * K_TOT) / (256 * 8), b256, 0, stream>>>(x, xbuf);
    gemm_bf16_k<<<(M_TOT / BM) * (N_TOT / BN), 512, 0, stream>>>(xbuf, wbuf, out);
  } else {
    gemm_fb_k<<<dim3(N_TOT / 64, M_TOT / 64), b256, 0, stream>>>(x, weight, mora, scale, out);
  }
}